// Round 3
// baseline (342.836 us; speedup 1.0000x reference)
//
#include <hip/hip_runtime.h>

// BatchSplitFF: DM=1024, NE=16, ES=4 (NES=64 expert pairs), ESZ=64,
// BATCH*SEQ = 8*2048 tokens -> 1024 groups of 16 tokens.
#define DM   1024
#define NES  64
#define ESZ  64
#define NG   1024
#define TOK  16

typedef __bf16 bf16;
typedef __bf16 bf16x4 __attribute__((ext_vector_type(4)));
typedef __bf16 bf16x8 __attribute__((ext_vector_type(8)));
typedef float  f32x4  __attribute__((ext_vector_type(4)));

// async global->LDS, 16B per lane, LDS dest = wave-uniform base + lane*16
__device__ __forceinline__ void gld_lds16(const bf16* g, bf16* s) {
    __builtin_amdgcn_global_load_lds(
        (const __attribute__((address_space(1))) void*)g,
        (__attribute__((address_space(3))) void*)s, 16, 0, 0);
}

// ---------------- K0: transpose weights to bf16, MFMA-friendly layouts ----
// f1 [d][es][f] -> f1p bf16 [es][f][d]   f2 [es][f][d] -> f2t bf16 [es][d][f]
__global__ __launch_bounds__(256) void k0_transpose(const float* __restrict__ f1,
                                                    const float* __restrict__ f2,
                                                    bf16* __restrict__ f1p,
                                                    bf16* __restrict__ f2t) {
    __shared__ float tile[64 * 65];
    const int es = blockIdx.y, d0 = blockIdx.x * 64, tid = threadIdx.x;
    #pragma unroll
    for (int i = 0; i < 4; ++i) {
        int idx = i * 256 + tid; int r = idx >> 4, c4 = (idx & 15) * 4;
        float4 v = *(const float4*)(f1 + (size_t)(d0 + r) * 4096 + es * 64 + c4);
        tile[r * 65 + c4] = v.x; tile[r * 65 + c4 + 1] = v.y;
        tile[r * 65 + c4 + 2] = v.z; tile[r * 65 + c4 + 3] = v.w;
    }
    __syncthreads();
    #pragma unroll
    for (int i = 0; i < 2; ++i) {
        int idx = i * 256 + tid; int f = idx >> 3, dl0 = (idx & 7) * 8;
        bf16x8 o;
        #pragma unroll
        for (int j = 0; j < 8; ++j) o[j] = (bf16)tile[(dl0 + j) * 65 + f];
        *(bf16x8*)(f1p + (size_t)es * 65536 + f * 1024 + d0 + dl0) = o;
    }
    __syncthreads();
    #pragma unroll
    for (int i = 0; i < 4; ++i) {
        int idx = i * 256 + tid; int r = idx >> 4, c4 = (idx & 15) * 4;
        float4 v = *(const float4*)(f2 + (size_t)es * 65536 + r * 1024 + d0 + c4);
        tile[r * 65 + c4] = v.x; tile[r * 65 + c4 + 1] = v.y;
        tile[r * 65 + c4 + 2] = v.z; tile[r * 65 + c4 + 3] = v.w;
    }
    __syncthreads();
    #pragma unroll
    for (int i = 0; i < 2; ++i) {
        int idx = i * 256 + tid; int dl = idx >> 3, f0 = (idx & 7) * 8;
        bf16x8 o;
        #pragma unroll
        for (int j = 0; j < 8; ++j) o[j] = (bf16)tile[(f0 + j) * 65 + dl];
        *(bf16x8*)(f2t + (size_t)es * 65536 + (size_t)(d0 + dl) * 64 + f0) = o;
    }
}

// ---------------- K1: fp32 logits + argmax + sel nibble-pack ----------------
// Round-4 structure: ctrl chunk [64 dl][64 es] staged into LDS (contiguous
// 16 KB copy, coalesced, conflict-free) so the hot loop's 4 ctrl reads per
// 4-dim step become conflict-free ds_read_b32 (64 consecutive dwords/wave)
// instead of latency-exposed scalar global loads. Chunk size 64 dims; both
// x and ctrl chunks are register-prefetched one chunk ahead (loads issued
// right after the compute barrier, consumed at the next store phase) so
// L2/LLC latency hides under the 16-iteration compute phase.
// The per-(t,es) fmac chain is VERBATIM from the passing rounds (single
// fmac per term, d strictly ascending 0..1023) -> BIT-IDENTICAL logits.
// WRITE_XB: also emits xb = bf16(x) (same RTN bits k2 would produce
// inline) from the already-loaded staging registers, so k2 can gather
// bf16 directly (halves its L2 read bytes, kills its cvt chain).
template<int WRITE_XB>
__global__ __launch_bounds__(256) void k1_logits(const float* __restrict__ x,
                                                 const float* __restrict__ ctrl,
                                                 int* __restrict__ sel,
                                                 unsigned* __restrict__ selp,
                                                 bf16* __restrict__ xb) {
    __shared__ __align__(16) float xs[TOK * 64];   // 4 KB  (chunk of 64 dims)
    __shared__ __align__(16) float cs[64 * 64];    // 16 KB (ctrl chunk [dl][es])
    __shared__ float sl[TOK * NES];
    __shared__ int   st[NES];
    const int bg  = blockIdx.x;
    const int tid = threadIdx.x;
    const int es  = tid & 63;
    const int tq  = tid >> 6;            // wave 0..3 -> rows tq*4 .. tq*4+3
    const float* xg = x + (size_t)bg * (TOK * DM);
    const int xr = tid >> 4, xc = (tid & 15) * 4;   // x staging coords
    float acc[4] = {0.f, 0.f, 0.f, 0.f};

    // prefetch registers: chunk c data
    float4 xv;
    float4 cv[4];
    xv = *(const float4*)(xg + xr * DM + xc);
    #pragma unroll
    for (int j = 0; j < 4; ++j)
        cv[j] = *(const float4*)(ctrl + (size_t)(tid + j * 256) * 4);

    for (int c = 0; c < 16; ++c) {
        const int d0 = c * 64;
        __syncthreads();            // previous compute done reading xs/cs
        *(float4*)(xs + xr * 64 + xc) = xv;
        if (WRITE_XB) {
            bf16x4 o = {(bf16)xv.x, (bf16)xv.y, (bf16)xv.z, (bf16)xv.w};
            *(bf16x4*)(xb + (size_t)(bg * TOK + xr) * DM + d0 + xc) = o;
        }
        #pragma unroll
        for (int j = 0; j < 4; ++j)
            *(float4*)(cs + tid * 4 + j * 1024) = cv[j];
        __syncthreads();            // chunk c visible
        if (c < 15) {               // prefetch chunk c+1 (hides under compute)
            xv = *(const float4*)(xg + xr * DM + d0 + 64 + xc);
            #pragma unroll
            for (int j = 0; j < 4; ++j)
                cv[j] = *(const float4*)(ctrl + (size_t)(d0 + 64) * 64 +
                                         (size_t)(tid + j * 256) * 4);
        }
        #pragma unroll
        for (int dl4 = 0; dl4 < 64; dl4 += 4) {
            float4 v0 = *(const float4*)(xs + (tq * 4 + 0) * 64 + dl4);
            float4 v1 = *(const float4*)(xs + (tq * 4 + 1) * 64 + dl4);
            float4 v2 = *(const float4*)(xs + (tq * 4 + 2) * 64 + dl4);
            float4 v3 = *(const float4*)(xs + (tq * 4 + 3) * 64 + dl4);
            float c0 = cs[(dl4 + 0) * 64 + es];
            float c1 = cs[(dl4 + 1) * 64 + es];
            float c2 = cs[(dl4 + 2) * 64 + es];
            float c3 = cs[(dl4 + 3) * 64 + es];
            acc[0] += v0.x * c0; acc[1] += v1.x * c0;
            acc[2] += v2.x * c0; acc[3] += v3.x * c0;
            acc[0] += v0.y * c1; acc[1] += v1.y * c1;
            acc[2] += v2.y * c1; acc[3] += v3.y * c1;
            acc[0] += v0.z * c2; acc[1] += v1.z * c2;
            acc[2] += v2.z * c2; acc[3] += v3.z * c2;
            acc[0] += v0.w * c3; acc[1] += v1.w * c3;
            acc[2] += v2.w * c3; acc[3] += v3.w * c3;
        }
    }
    #pragma unroll
    for (int i = 0; i < 4; ++i) {
        int t = tq * 4 + i;
        sl[t * NES + es] = acc[i] + (float)t * (1e-6f / 15.f);
    }
    __syncthreads();
    if (tid < NES) {
        float best = -1e30f; int bi = 0;
        #pragma unroll
        for (int t = 0; t < TOK; ++t) {
            float v = sl[t * NES + tid];
            if (v >= best) { best = v; bi = t; }   // >= : later t wins ties
        }
        sel[bg * NES + tid] = bi;
        st[tid] = bi;
    }
    __syncthreads();
    if (tid < 8) {   // pack 8 es per dword, 4-bit each
        unsigned p = 0;
        #pragma unroll
        for (int k = 0; k < 8; ++k) p |= (unsigned)st[tid * 8 + k] << (4 * k);
        selp[bg * 8 + tid] = p;
    }
}

// ---------------- K2: FFN1 (gather + GEMM + bias + relu) ----------------
// Round-4 structure: 64-group blocks (grid 16x64 = 1024 blocks = 4/CU,
// doubles occupancy to 16 waves/CU) + register-prefetch of the next k-step's
// A/B data (loads issued after barrier-1, overlapping frag reads + MFMA).
// USE_XB: gathers pre-converted bf16 rows from xb (same RTN bits as the
// inline cvt -> bit-identical inner; half the L2/LLC read bytes).
// MFMA sequence per (row,f) output is unchanged (k0 ascending, one mfma
// per 32 dims) -> bit-identical to the passing rounds.
template<int USE_XB>
__global__ __launch_bounds__(256) void k2_ffn1(const float* __restrict__ x,
                                               const bf16* __restrict__ xb,
                                               const bf16* __restrict__ f1p,
                                               const float* __restrict__ bias,
                                               const int* __restrict__ sel,
                                               bf16* __restrict__ inner) {
    __shared__ int  sel_s[64];
    __shared__ __align__(16) bf16 As[64 * 40];
    __shared__ __align__(16) bf16 Bs[64 * 40];
    const int es  = blockIdx.y;
    const int g0  = blockIdx.x * 64;
    const int tid = threadIdx.x;
    if (tid < 64) sel_s[tid] = sel[(size_t)(g0 + tid) * 64 + es];
    __syncthreads();

    const int w = tid >> 6, l = tid & 63, quad = l >> 4, lr = l & 15;
    const int rowq = tid >> 2, colq = (tid & 3) * 8;   // bf16x8 stage coords
    const int row8 = tid >> 3, c4 = (tid & 7) * 4;     // fp32-path coords
    const bf16* f1es = f1p + (size_t)es * (DM * ESZ);

    int tokq = 0, tok0 = 0, tok1 = 0;
    if (USE_XB) {
        tokq = (g0 + rowq) * 16 + sel_s[rowq];
    } else {
        tok0 = (g0 + row8) * 16 + sel_s[row8];
        tok1 = (g0 + 32 + row8) * 16 + sel_s[32 + row8];
    }

    // prefetch registers for step k0=0
    bf16x8 ra, rb;
    float4 r0, r1;
    if (USE_XB) {
        ra = *(const bf16x8*)(xb + (size_t)tokq * DM + colq);
    } else {
        r0 = *(const float4*)(x + (size_t)tok0 * DM + c4);
        r1 = *(const float4*)(x + (size_t)tok1 * DM + c4);
    }
    rb = *(const bf16x8*)(f1es + rowq * 1024 + colq);

    f32x4 acc[4];
    #pragma unroll
    for (int nt = 0; nt < 4; ++nt) acc[nt] = (f32x4){0.f, 0.f, 0.f, 0.f};

    for (int k0 = 0; k0 < DM; k0 += 32) {
        if (USE_XB) {
            *(bf16x8*)(As + rowq * 40 + colq) = ra;
        } else {
            bf16x4 o0 = {(bf16)r0.x, (bf16)r0.y, (bf16)r0.z, (bf16)r0.w};
            bf16x4 o1 = {(bf16)r1.x, (bf16)r1.y, (bf16)r1.z, (bf16)r1.w};
            *(bf16x4*)(As + row8 * 40 + c4) = o0;
            *(bf16x4*)(As + (32 + row8) * 40 + c4) = o1;
        }
        *(bf16x8*)(Bs + rowq * 40 + colq) = rb;
        __syncthreads();
        if (k0 + 32 < DM) {   // prefetch next step (overlaps frag reads+MFMA)
            if (USE_XB) {
                ra = *(const bf16x8*)(xb + (size_t)tokq * DM + k0 + 32 + colq);
            } else {
                r0 = *(const float4*)(x + (size_t)tok0 * DM + k0 + 32 + c4);
                r1 = *(const float4*)(x + (size_t)tok1 * DM + k0 + 32 + c4);
            }
            rb = *(const bf16x8*)(f1es + rowq * 1024 + k0 + 32 + colq);
        }
        bf16x8 av = *(const bf16x8*)(As + (w * 16 + lr) * 40 + quad * 8);
        bf16x8 bv[4];
        #pragma unroll
        for (int nt = 0; nt < 4; ++nt)
            bv[nt] = *(const bf16x8*)(Bs + (nt * 16 + lr) * 40 + quad * 8);
        #pragma unroll
        for (int nt = 0; nt < 4; ++nt)
            acc[nt] = __builtin_amdgcn_mfma_f32_16x16x32_bf16(av, bv[nt], acc[nt], 0, 0, 0);
        __syncthreads();
    }
    bf16* innes = inner + (size_t)es * (NG * ESZ);
    #pragma unroll
    for (int nt = 0; nt < 4; ++nt) {
        int f = nt * 16 + lr;
        float b = bias[es * 64 + f];
        #pragma unroll
        for (int r = 0; r < 4; ++r) {
            int grow = w * 16 + quad * 4 + r;
            float v = acc[nt][r] + b;
            v = v > 0.f ? v : 0.f;
            innes[(size_t)(g0 + grow) * 64 + f] = (bf16)v;
        }
    }
}

// ---------------- K3: FFN2 + un-permute scatter ----------------
// Unchanged from round 2 (125 -> ~65 us there): LDS-staged A/B via
// global_load_lds width=16, double-buffered, counted vmcnt(2), source-side
// XOR swizzle, race-free accs scatter, nontemporal out stores.
__global__ __launch_bounds__(256) void k3_ffn2(const bf16* __restrict__ inner,
                                               const bf16* __restrict__ f2t,
                                               const unsigned* __restrict__ selp,
                                               float* __restrict__ out) {
    __shared__ float accs[512 * 32];                 // 64 KB
    __shared__ __align__(16) bf16 As[2][32 * 64];    // 8 KB (2 x 4 KB tiles)
    __shared__ __align__(16) bf16 Bs[2][32 * 64];    // 8 KB   -> 80 KB total, 2 blk/CU
    const int d0  = blockIdx.x * 32;
    const int g0  = blockIdx.y * 32;
    const int tid = threadIdx.x;
    const int w = tid >> 6, l = tid & 63, quad = l >> 4, lr = l & 15;
    const int mh = w >> 1, nh = w & 1;

    unsigned sp[4][8];
    #pragma unroll
    for (int r = 0; r < 4; ++r) {
        int gl = mh * 16 + quad * 4 + r;
        uint4 a = *(const uint4*)(selp + (size_t)(g0 + gl) * 8);
        uint4 b = *(const uint4*)(selp + (size_t)(g0 + gl) * 8 + 4);
        sp[r][0] = a.x; sp[r][1] = a.y; sp[r][2] = a.z; sp[r][3] = a.w;
        sp[r][4] = b.x; sp[r][5] = b.y; sp[r][6] = b.z; sp[r][7] = b.w;
    }

    const int srow = tid >> 3;
    const int scb  = ((tid & 7) * 16) ^ ((srow & 7) << 4);
    const bf16* srcA = inner + (size_t)(g0 + srow) * 64 + (scb >> 1);
    const bf16* srcB = f2t   + (size_t)(d0 + srow) * 64 + (scb >> 1);
    bf16* dA0 = &As[0][w * 512]; bf16* dA1 = &As[1][w * 512];
    bf16* dB0 = &Bs[0][w * 512]; bf16* dB1 = &Bs[1][w * 512];

    #pragma unroll
    for (int i = 0; i < 16; ++i)
        ((f32x4*)accs)[i * 256 + tid] = (f32x4){0.f, 0.f, 0.f, 0.f};

    gld_lds16(srcA, dA0);
    gld_lds16(srcB, dB0);
    __syncthreads();

    const int rowA = mh * 16 + lr, rowB = nh * 16 + lr;
    const int offA0 = rowA * 128 + ((quad * 16)      ^ ((rowA & 7) << 4));
    const int offA1 = rowA * 128 + ((quad * 16 + 64) ^ ((rowA & 7) << 4));
    const int offB0 = rowB * 128 + ((quad * 16)      ^ ((rowB & 7) << 4));
    const int offB1 = rowB * 128 + ((quad * 16 + 64) ^ ((rowB & 7) << 4));

    #pragma unroll
    for (int es = 0; es < 64; ++es) {
        const int cur = es & 1;
        if (es < 63) {
            if (cur == 0) { gld_lds16(srcA + (size_t)(es + 1) * 65536, dA1);
                            gld_lds16(srcB + (size_t)(es + 1) * 65536, dB1); }
            else          { gld_lds16(srcA + (size_t)(es + 1) * 65536, dA0);
                            gld_lds16(srcB + (size_t)(es + 1) * 65536, dB0); }
            asm volatile("s_waitcnt vmcnt(2)" ::: "memory");
        } else {
            asm volatile("s_waitcnt vmcnt(0)" ::: "memory");
        }
        asm volatile("s_barrier" ::: "memory");

        const char* a = (const char*)As[cur];
        const char* b = (const char*)Bs[cur];
        bf16x8 a0 = *(const bf16x8*)(a + offA0);
        bf16x8 a1 = *(const bf16x8*)(a + offA1);
        bf16x8 b0 = *(const bf16x8*)(b + offB0);
        bf16x8 b1 = *(const bf16x8*)(b + offB1);
        f32x4 z = {0.f, 0.f, 0.f, 0.f};
        z = __builtin_amdgcn_mfma_f32_16x16x32_bf16(a0, b0, z, 0, 0, 0);
        z = __builtin_amdgcn_mfma_f32_16x16x32_bf16(a1, b1, z, 0, 0, 0);

        const int dw = es >> 3, sh = (es & 7) * 4;
        #pragma unroll
        for (int r = 0; r < 4; ++r) {
            int t    = (sp[r][dw] >> sh) & 15;
            int gl   = mh * 16 + quad * 4 + r;
            int scol = (nh * 16 + lr) ^ ((t & 7) << 2);
            accs[(gl * 16 + t) * 32 + scol] += z[r];
        }
        asm volatile("s_barrier" ::: "memory");
    }
    __syncthreads();
    #pragma unroll
    for (int i = 0; i < 16; ++i) {
        int fi = i * 256 + tid;
        int row = fi >> 3, q = fi & 7;
        int scol4 = (q * 4) ^ ((row & 7) << 2);
        f32x4 v = *(f32x4*)(accs + row * 32 + scol4);
        __builtin_nontemporal_store(v, (f32x4*)(out + (size_t)(g0 * 16 + row) * DM + d0 + q * 4));
    }
}

extern "C" void kernel_launch(void* const* d_in, const int* in_sizes, int n_in,
                              void* d_out, int out_size, void* d_ws, size_t ws_size,
                              hipStream_t stream) {
    const float* x    = (const float*)d_in[0];
    const float* ctrl = (const float*)d_in[1];
    const float* f1   = (const float*)d_in[2];
    const float* f2   = (const float*)d_in[3];
    const float* bias = (const float*)d_in[4];
    float* out = (float*)d_out;

    char* ws = (char*)d_ws;
    bf16*     f1p   = (bf16*)(ws);                  // 8,388,608 B
    bf16*     f2t   = (bf16*)(ws + 8388608);        // 8,388,608 B
    bf16*     inner = (bf16*)(ws + 16777216);       // 8,388,608 B
    int*      sel   = (int*)(ws + 25165824);        //   262,144 B
    unsigned* selp  = (unsigned*)(ws + 25427968);   //    32,768 B
    bf16*     xb    = (bf16*)(ws + 25460736);       // 33,554,432 B (optional)

    const size_t need_xb = (size_t)25460736 + (size_t)NG * TOK * DM * sizeof(bf16);
    const bool use_xb = ws_size >= need_xb;

    hipLaunchKernelGGL(k0_transpose, dim3(16, 64), dim3(256), 0, stream, f1, f2, f1p, f2t);
    if (use_xb) {
        hipLaunchKernelGGL((k1_logits<1>), dim3(1024), dim3(256), 0, stream, x, ctrl, sel, selp, xb);
        hipLaunchKernelGGL((k2_ffn1<1>),   dim3(16, 64), dim3(256), 0, stream, x, xb, f1p, bias, sel, inner);
    } else {
        hipLaunchKernelGGL((k1_logits<0>), dim3(1024), dim3(256), 0, stream, x, ctrl, sel, selp, xb);
        hipLaunchKernelGGL((k2_ffn1<0>),   dim3(16, 64), dim3(256), 0, stream, x, xb, f1p, bias, sel, inner);
    }
    hipLaunchKernelGGL(k3_ffn2, dim3(32, 32), dim3(256), 0, stream, inner, f2t, selp, out);
}